// Round 1
// baseline (6275.245 us; speedup 1.0000x reference)
//
#include <hip/hip_runtime.h>
#include <math.h>

#define Cn 256
#define Ln 256
#define Bn 2
#define ROWS 8
#define H1 1024  // 4*C

__device__ __forceinline__ float gelu_exact(float x) {
    return 0.5f * x * (1.0f + erff(x * 0.70710678118654752f));
}

// mod = silu(c_BD) @ ada_w.T + ada_b   -> (B, 3C) into workspace
__global__ __launch_bounds__(256) void mod_kernel(
    const float* __restrict__ c_BD, const float* __restrict__ ada_w,
    const float* __restrict__ ada_b, float* __restrict__ mod)
{
    int o = blockIdx.x * 256 + threadIdx.x;   // 0..1535
    int b = o / (3 * Cn);
    int j = o - b * (3 * Cn);
    const float* crow = c_BD + b * Cn;
    const float* wrow = ada_w + (size_t)j * Cn;
    float acc = 0.f;
    for (int k = 0; k < Cn; k += 4) {
        float4 cv = *(const float4*)(crow + k);
        float4 wv = *(const float4*)(wrow + k);
        float s0 = cv.x / (1.f + expf(-cv.x));
        float s1 = cv.y / (1.f + expf(-cv.y));
        float s2 = cv.z / (1.f + expf(-cv.z));
        float s3 = cv.w / (1.f + expf(-cv.w));
        acc += s0 * wv.x + s1 * wv.y + s2 * wv.z + s3 * wv.w;
    }
    mod[o] = acc + ada_b[j];
}

__global__ __launch_bounds__(256) void main_kernel(
    const float* __restrict__ x, const float* __restrict__ embed_w,
    const float* __restrict__ pos_w, const float* __restrict__ bins,
    const float* __restrict__ ln_g, const float* __restrict__ ln_b,
    const float* __restrict__ fc1_w, const float* __restrict__ fc1_b,
    const float* __restrict__ fc2_w, const float* __restrict__ fc2_b,
    const float* __restrict__ mod, float* __restrict__ out)
{
    __shared__ float s_tile[ROWS][Cn];   // pre-LN modulated s (needed for residual)
    __shared__ float h_tile[ROWS][Cn];   // LN output (GEMM1 input)
    __shared__ float g_tile[ROWS][H1];   // gelu(fc1) (GEMM2 input)
    __shared__ float bins_s[64];

    const int tid  = threadIdx.x;
    const int wave = tid >> 6;
    const int lane = tid & 63;

    const long base = (long)blockIdx.x * ROWS;       // flat row base in [0, B*L*L)
    const int  b    = (int)(base / (Ln * Ln));
    const int  rem  = (int)(base % (Ln * Ln));
    const int  i    = rem / Ln;
    const int  j0   = rem % Ln;                      // 8 consecutive j, same (b,i)

    if (tid < 63) bins_s[tid] = bins[tid];
    __syncthreads();

    const float* xi = x + ((long)b * Ln + i) * 3;
    const float xi0 = xi[0], xi1 = xi[1], xi2 = xi[2];
    const float* modb = mod + b * (3 * Cn);

    // ---- Phase 1: build s + LayerNorm. One wave per row (2 rows/wave). ----
    for (int rr = wave; rr < ROWS; rr += 4) {
        const int j = j0 + rr;
        const float* xj = x + ((long)b * Ln + j) * 3;
        const float d0 = xi0 - xj[0], d1 = xi1 - xj[1], d2 = xi2 - xj[2];
        const float d = d0 * d0 + d1 * d1 + d2 * d2;
        int idx = 0;
        #pragma unroll
        for (int k = 0; k < 63; ++k) idx += (bins_s[k] < d) ? 1 : 0;
        int rel = i - j;
        rel = (rel < -64 ? -64 : (rel > 63 ? 63 : rel)) + 64;
        const float* erow = embed_w + (size_t)idx * Cn;
        const float* prow = pos_w + (size_t)rel * Cn;

        float sv[4];
        float partial = 0.f;
        #pragma unroll
        for (int m = 0; m < 4; ++m) {
            const int c = lane + 64 * m;
            const float e  = erow[c] + prow[c];
            const float v  = e * (1.f + modb[Cn + c]) + modb[c];
            sv[m] = v;
            partial += v;
        }
        float sum = partial;
        #pragma unroll
        for (int off = 32; off; off >>= 1) sum += __shfl_xor(sum, off, 64);
        const float mu = sum * (1.f / Cn);
        float p2 = 0.f;
        #pragma unroll
        for (int m = 0; m < 4; ++m) { const float t = sv[m] - mu; p2 += t * t; }
        float vs = p2;
        #pragma unroll
        for (int off = 32; off; off >>= 1) vs += __shfl_xor(vs, off, 64);
        const float rstd = rsqrtf(vs * (1.f / Cn) + 1e-5f);
        #pragma unroll
        for (int m = 0; m < 4; ++m) {
            const int c = lane + 64 * m;
            s_tile[rr][c] = sv[m];
            h_tile[rr][c] = (sv[m] - mu) * rstd * ln_g[c] + ln_b[c];
        }
    }
    __syncthreads();

    // ---- Phase 2: GEMM1 (8x256 @ 256x1024) + bias + exact GELU -> g_tile ----
    {
        float acc[ROWS][4];
        #pragma unroll
        for (int r = 0; r < ROWS; ++r)
            #pragma unroll
            for (int m = 0; m < 4; ++m) acc[r][m] = 0.f;

        const float* w0 = fc1_w + (size_t)(4 * tid + 0) * Cn;
        const float* w1 = fc1_w + (size_t)(4 * tid + 1) * Cn;
        const float* w2 = fc1_w + (size_t)(4 * tid + 2) * Cn;
        const float* w3 = fc1_w + (size_t)(4 * tid + 3) * Cn;

        for (int k = 0; k < Cn; k += 4) {
            const float4 a0 = *(const float4*)(w0 + k);
            const float4 a1 = *(const float4*)(w1 + k);
            const float4 a2 = *(const float4*)(w2 + k);
            const float4 a3 = *(const float4*)(w3 + k);
            #pragma unroll
            for (int r = 0; r < ROWS; ++r) {
                const float4 h4 = *(const float4*)(&h_tile[r][k]);  // LDS broadcast
                acc[r][0] += h4.x * a0.x + h4.y * a0.y + h4.z * a0.z + h4.w * a0.w;
                acc[r][1] += h4.x * a1.x + h4.y * a1.y + h4.z * a1.z + h4.w * a1.w;
                acc[r][2] += h4.x * a2.x + h4.y * a2.y + h4.z * a2.z + h4.w * a2.w;
                acc[r][3] += h4.x * a3.x + h4.y * a3.y + h4.z * a3.z + h4.w * a3.w;
            }
        }
        const float b0 = fc1_b[4 * tid + 0];
        const float b1 = fc1_b[4 * tid + 1];
        const float b2 = fc1_b[4 * tid + 2];
        const float b3 = fc1_b[4 * tid + 3];
        #pragma unroll
        for (int r = 0; r < ROWS; ++r) {
            float4 g;
            g.x = gelu_exact(acc[r][0] + b0);
            g.y = gelu_exact(acc[r][1] + b1);
            g.z = gelu_exact(acc[r][2] + b2);
            g.w = gelu_exact(acc[r][3] + b3);
            *(float4*)(&g_tile[r][4 * tid]) = g;   // consecutive 16B per thread
        }
    }
    __syncthreads();

    // ---- Phase 3: GEMM2 (8x1024 @ 1024x256) + bias + gated residual ----
    {
        float acc2[ROWS];
        #pragma unroll
        for (int r = 0; r < ROWS; ++r) acc2[r] = 0.f;

        const float* w2r = fc2_w + (size_t)tid * H1;
        for (int k = 0; k < H1; k += 4) {
            const float4 wv = *(const float4*)(w2r + k);
            #pragma unroll
            for (int r = 0; r < ROWS; ++r) {
                const float4 g = *(const float4*)(&g_tile[r][k]);  // LDS broadcast
                acc2[r] += g.x * wv.x + g.y * wv.y + g.z * wv.z + g.w * wv.w;
            }
        }
        const float bias  = fc2_b[tid];
        const float gate  = modb[2 * Cn + tid];
        #pragma unroll
        for (int r = 0; r < ROWS; ++r) {
            const float v = acc2[r] + bias;
            out[(base + r) * Cn + tid] = s_tile[r][tid] + gate * v;
        }
    }
}

extern "C" void kernel_launch(void* const* d_in, const int* in_sizes, int n_in,
                              void* d_out, int out_size, void* d_ws, size_t ws_size,
                              hipStream_t stream) {
    const float* x_BLD   = (const float*)d_in[0];
    const float* c_BD    = (const float*)d_in[1];
    const float* embed_w = (const float*)d_in[2];
    const float* pos_w   = (const float*)d_in[3];
    const float* bins    = (const float*)d_in[4];
    const float* ada_w   = (const float*)d_in[5];
    const float* ada_b   = (const float*)d_in[6];
    const float* ln_g    = (const float*)d_in[7];
    const float* ln_b    = (const float*)d_in[8];
    const float* fc1_w   = (const float*)d_in[9];
    const float* fc1_b   = (const float*)d_in[10];
    const float* fc2_w   = (const float*)d_in[11];
    const float* fc2_b   = (const float*)d_in[12];
    float* out = (float*)d_out;
    float* mod = (float*)d_ws;   // B * 3C = 1536 floats

    mod_kernel<<<(Bn * 3 * Cn) / 256, 256, 0, stream>>>(c_BD, ada_w, ada_b, mod);

    const int n_rows = Bn * Ln * Ln;            // 131072
    main_kernel<<<n_rows / ROWS, 256, 0, stream>>>(
        x_BLD, embed_w, pos_w, bins, ln_g, ln_b,
        fc1_w, fc1_b, fc2_w, fc2_b, mod, out);
}

// Round 2
// 966.776 us; speedup vs baseline: 6.4909x; 6.4909x over previous
//
#include <hip/hip_runtime.h>
#include <math.h>

#define Cn 256
#define Ln 256
#define Bn 2
#define ROWS 8
#define H1 1024   // 4*C
#define NIDX 64
#define NREL 128
#define NCOMBO (Bn * NIDX * NREL)   // 16384

__device__ __forceinline__ float gelu_exact(float x) {
    return 0.5f * x * (1.0f + erff(x * 0.70710678118654752f));
}

// mod = silu(c_BD) @ ada_w.T + ada_b   -> (B, 3C) into workspace
__global__ __launch_bounds__(256) void mod_kernel(
    const float* __restrict__ c_BD, const float* __restrict__ ada_w,
    const float* __restrict__ ada_b, float* __restrict__ mod)
{
    int o = blockIdx.x * 256 + threadIdx.x;   // 0..1535
    int b = o / (3 * Cn);
    int j = o - b * (3 * Cn);
    const float* crow = c_BD + b * Cn;
    const float* wrow = ada_w + (size_t)j * Cn;
    float acc = 0.f;
    for (int k = 0; k < Cn; k += 4) {
        float4 cv = *(const float4*)(crow + k);
        float4 wv = *(const float4*)(wrow + k);
        float s0 = cv.x / (1.f + expf(-cv.x));
        float s1 = cv.y / (1.f + expf(-cv.y));
        float s2 = cv.z / (1.f + expf(-cv.z));
        float s3 = cv.w / (1.f + expf(-cv.w));
        acc += s0 * wv.x + s1 * wv.y + s2 * wv.z + s3 * wv.w;
    }
    mod[o] = acc + ada_b[j];
}

// Computes table[(b*NIDX+idx)*NREL+rel][C] = s + gate * MLP(LN(s))
// for all 16384 distinct (b, idx, rel) combos. 8 rows per block.
__global__ __launch_bounds__(256) void table_kernel(
    const float* __restrict__ embed_w, const float* __restrict__ pos_w,
    const float* __restrict__ ln_g, const float* __restrict__ ln_b,
    const float* __restrict__ fc1_w, const float* __restrict__ fc1_b,
    const float* __restrict__ fc2_w, const float* __restrict__ fc2_b,
    const float* __restrict__ mod, float* __restrict__ table)
{
    __shared__ float s_tile[ROWS][Cn];
    __shared__ float h_tile[ROWS][Cn];
    __shared__ float g_tile[ROWS][H1];

    const int tid  = threadIdx.x;
    const int wave = tid >> 6;
    const int lane = tid & 63;

    const int base = blockIdx.x * ROWS;      // combo id; 8 consecutive rel
    const int b    = base >> 13;             // /(64*128)
    const int idx  = (base >> 7) & 63;
    const int rel0 = base & 127;

    const float* modb = mod + b * (3 * Cn);
    const float* erow = embed_w + (size_t)idx * Cn;

    // ---- Phase 1: build s + LayerNorm. One wave per row (2 rows/wave). ----
    for (int rr = wave; rr < ROWS; rr += 4) {
        const float* prow = pos_w + (size_t)(rel0 + rr) * Cn;
        float sv[4];
        float partial = 0.f;
        #pragma unroll
        for (int m = 0; m < 4; ++m) {
            const int c = lane + 64 * m;
            const float e = erow[c] + prow[c];
            const float v = e * (1.f + modb[Cn + c]) + modb[c];
            sv[m] = v;
            partial += v;
        }
        float sum = partial;
        #pragma unroll
        for (int off = 32; off; off >>= 1) sum += __shfl_xor(sum, off, 64);
        const float mu = sum * (1.f / Cn);
        float p2 = 0.f;
        #pragma unroll
        for (int m = 0; m < 4; ++m) { const float t = sv[m] - mu; p2 += t * t; }
        float vs = p2;
        #pragma unroll
        for (int off = 32; off; off >>= 1) vs += __shfl_xor(vs, off, 64);
        const float rstd = rsqrtf(vs * (1.f / Cn) + 1e-5f);
        #pragma unroll
        for (int m = 0; m < 4; ++m) {
            const int c = lane + 64 * m;
            s_tile[rr][c] = sv[m];
            h_tile[rr][c] = (sv[m] - mu) * rstd * ln_g[c] + ln_b[c];
        }
    }
    __syncthreads();

    // ---- Phase 2: GEMM1 (8x256 @ 256x1024) + bias + exact GELU -> g_tile ----
    {
        float acc[ROWS][4];
        #pragma unroll
        for (int r = 0; r < ROWS; ++r)
            #pragma unroll
            for (int m = 0; m < 4; ++m) acc[r][m] = 0.f;

        const float* w0 = fc1_w + (size_t)(4 * tid + 0) * Cn;
        const float* w1 = fc1_w + (size_t)(4 * tid + 1) * Cn;
        const float* w2 = fc1_w + (size_t)(4 * tid + 2) * Cn;
        const float* w3 = fc1_w + (size_t)(4 * tid + 3) * Cn;

        for (int k = 0; k < Cn; k += 4) {
            const float4 a0 = *(const float4*)(w0 + k);
            const float4 a1 = *(const float4*)(w1 + k);
            const float4 a2 = *(const float4*)(w2 + k);
            const float4 a3 = *(const float4*)(w3 + k);
            #pragma unroll
            for (int r = 0; r < ROWS; ++r) {
                const float4 h4 = *(const float4*)(&h_tile[r][k]);  // LDS broadcast
                acc[r][0] += h4.x * a0.x + h4.y * a0.y + h4.z * a0.z + h4.w * a0.w;
                acc[r][1] += h4.x * a1.x + h4.y * a1.y + h4.z * a1.z + h4.w * a1.w;
                acc[r][2] += h4.x * a2.x + h4.y * a2.y + h4.z * a2.z + h4.w * a2.w;
                acc[r][3] += h4.x * a3.x + h4.y * a3.y + h4.z * a3.z + h4.w * a3.w;
            }
        }
        const float b0 = fc1_b[4 * tid + 0];
        const float b1 = fc1_b[4 * tid + 1];
        const float b2 = fc1_b[4 * tid + 2];
        const float b3 = fc1_b[4 * tid + 3];
        #pragma unroll
        for (int r = 0; r < ROWS; ++r) {
            float4 g;
            g.x = gelu_exact(acc[r][0] + b0);
            g.y = gelu_exact(acc[r][1] + b1);
            g.z = gelu_exact(acc[r][2] + b2);
            g.w = gelu_exact(acc[r][3] + b3);
            *(float4*)(&g_tile[r][4 * tid]) = g;
        }
    }
    __syncthreads();

    // ---- Phase 3: GEMM2 (8x1024 @ 1024x256) + bias + gated residual ----
    {
        float acc2[ROWS];
        #pragma unroll
        for (int r = 0; r < ROWS; ++r) acc2[r] = 0.f;

        const float* w2r = fc2_w + (size_t)tid * H1;
        for (int k = 0; k < H1; k += 4) {
            const float4 wv = *(const float4*)(w2r + k);
            #pragma unroll
            for (int r = 0; r < ROWS; ++r) {
                const float4 g = *(const float4*)(&g_tile[r][k]);  // LDS broadcast
                acc2[r] += g.x * wv.x + g.y * wv.y + g.z * wv.z + g.w * wv.w;
            }
        }
        const float bias = fc2_b[tid];
        const float gate = modb[2 * Cn + tid];
        #pragma unroll
        for (int r = 0; r < ROWS; ++r) {
            const float v = acc2[r] + bias;
            table[(size_t)(base + r) * Cn + tid] = s_tile[r][tid] + gate * v;
        }
    }
}

// For each (b,i,j): idx from distance, rel from i-j, copy table row to out.
// grid = B*L*4 blocks; block (b, i, quarter) handles 64 j's (16 per wave).
__global__ __launch_bounds__(256) void gather_kernel(
    const float* __restrict__ x, const float* __restrict__ bins,
    const float* __restrict__ table, float* __restrict__ out)
{
    __shared__ float xs[Ln * 3];
    __shared__ float bins_s[63];

    const int tid = threadIdx.x;
    const int blk = blockIdx.x;          // (b*256 + i)*4 + q
    const int q   = blk & 3;
    const int bi  = blk >> 2;
    const int b   = bi >> 8;
    const int i   = bi & 255;

    for (int t = tid; t < Ln * 3; t += 256) xs[t] = x[(size_t)b * Ln * 3 + t];
    if (tid < 63) bins_s[tid] = bins[tid];
    __syncthreads();

    const float xi0 = xs[3 * i], xi1 = xs[3 * i + 1], xi2 = xs[3 * i + 2];
    const int wave = tid >> 6;
    const int lane = tid & 63;

    float4* outp = (float4*)(out + (size_t)bi * Ln * Cn);
    const float4* tab4 = (const float4*)table;

    // this block's j range: q*64 .. q*64+63; wave handles 16 of them
    #pragma unroll 2
    for (int jj = 0; jj < 16; ++jj) {
        const int j = q * 64 + wave * 16 + jj;
        const float d0 = xi0 - xs[3 * j];
        const float d1 = xi1 - xs[3 * j + 1];
        const float d2 = xi2 - xs[3 * j + 2];
        const float d = d0 * d0 + d1 * d1 + d2 * d2;
        int idx = 0;
        #pragma unroll
        for (int k = 0; k < 63; ++k) idx += (bins_s[k] < d) ? 1 : 0;
        int rel = i - j;
        rel = (rel < -64 ? -64 : (rel > 63 ? 63 : rel)) + 64;
        const size_t trow = (size_t)((b * NIDX + idx) * NREL + rel) * (Cn / 4);
        outp[(size_t)j * (Cn / 4) + lane] = tab4[trow + lane];
    }
}

// ---------------- fallback (round-1 path) if workspace is too small ---------
__global__ __launch_bounds__(256) void main_kernel_fb(
    const float* __restrict__ x, const float* __restrict__ embed_w,
    const float* __restrict__ pos_w, const float* __restrict__ bins,
    const float* __restrict__ ln_g, const float* __restrict__ ln_b,
    const float* __restrict__ fc1_w, const float* __restrict__ fc1_b,
    const float* __restrict__ fc2_w, const float* __restrict__ fc2_b,
    const float* __restrict__ mod, float* __restrict__ out)
{
    __shared__ float s_tile[ROWS][Cn];
    __shared__ float h_tile[ROWS][Cn];
    __shared__ float g_tile[ROWS][H1];
    __shared__ float bins_s[64];

    const int tid  = threadIdx.x;
    const int wave = tid >> 6;
    const int lane = tid & 63;

    const long base = (long)blockIdx.x * ROWS;
    const int  b    = (int)(base / (Ln * Ln));
    const int  rem  = (int)(base % (Ln * Ln));
    const int  i    = rem / Ln;
    const int  j0   = rem % Ln;

    if (tid < 63) bins_s[tid] = bins[tid];
    __syncthreads();

    const float* xi = x + ((long)b * Ln + i) * 3;
    const float xi0 = xi[0], xi1 = xi[1], xi2 = xi[2];
    const float* modb = mod + b * (3 * Cn);

    for (int rr = wave; rr < ROWS; rr += 4) {
        const int j = j0 + rr;
        const float* xj = x + ((long)b * Ln + j) * 3;
        const float d0 = xi0 - xj[0], d1 = xi1 - xj[1], d2 = xi2 - xj[2];
        const float d = d0 * d0 + d1 * d1 + d2 * d2;
        int idx = 0;
        #pragma unroll
        for (int k = 0; k < 63; ++k) idx += (bins_s[k] < d) ? 1 : 0;
        int rel = i - j;
        rel = (rel < -64 ? -64 : (rel > 63 ? 63 : rel)) + 64;
        const float* erow = embed_w + (size_t)idx * Cn;
        const float* prow = pos_w + (size_t)rel * Cn;

        float sv[4];
        float partial = 0.f;
        #pragma unroll
        for (int m = 0; m < 4; ++m) {
            const int c = lane + 64 * m;
            const float e  = erow[c] + prow[c];
            const float v  = e * (1.f + modb[Cn + c]) + modb[c];
            sv[m] = v;
            partial += v;
        }
        float sum = partial;
        #pragma unroll
        for (int off = 32; off; off >>= 1) sum += __shfl_xor(sum, off, 64);
        const float mu = sum * (1.f / Cn);
        float p2 = 0.f;
        #pragma unroll
        for (int m = 0; m < 4; ++m) { const float t = sv[m] - mu; p2 += t * t; }
        float vs = p2;
        #pragma unroll
        for (int off = 32; off; off >>= 1) vs += __shfl_xor(vs, off, 64);
        const float rstd = rsqrtf(vs * (1.f / Cn) + 1e-5f);
        #pragma unroll
        for (int m = 0; m < 4; ++m) {
            const int c = lane + 64 * m;
            s_tile[rr][c] = sv[m];
            h_tile[rr][c] = (sv[m] - mu) * rstd * ln_g[c] + ln_b[c];
        }
    }
    __syncthreads();

    {
        float acc[ROWS][4];
        #pragma unroll
        for (int r = 0; r < ROWS; ++r)
            #pragma unroll
            for (int m = 0; m < 4; ++m) acc[r][m] = 0.f;

        const float* w0 = fc1_w + (size_t)(4 * tid + 0) * Cn;
        const float* w1 = fc1_w + (size_t)(4 * tid + 1) * Cn;
        const float* w2 = fc1_w + (size_t)(4 * tid + 2) * Cn;
        const float* w3 = fc1_w + (size_t)(4 * tid + 3) * Cn;

        for (int k = 0; k < Cn; k += 4) {
            const float4 a0 = *(const float4*)(w0 + k);
            const float4 a1 = *(const float4*)(w1 + k);
            const float4 a2 = *(const float4*)(w2 + k);
            const float4 a3 = *(const float4*)(w3 + k);
            #pragma unroll
            for (int r = 0; r < ROWS; ++r) {
                const float4 h4 = *(const float4*)(&h_tile[r][k]);
                acc[r][0] += h4.x * a0.x + h4.y * a0.y + h4.z * a0.z + h4.w * a0.w;
                acc[r][1] += h4.x * a1.x + h4.y * a1.y + h4.z * a1.z + h4.w * a1.w;
                acc[r][2] += h4.x * a2.x + h4.y * a2.y + h4.z * a2.z + h4.w * a2.w;
                acc[r][3] += h4.x * a3.x + h4.y * a3.y + h4.z * a3.z + h4.w * a3.w;
            }
        }
        const float b0 = fc1_b[4 * tid + 0];
        const float b1 = fc1_b[4 * tid + 1];
        const float b2 = fc1_b[4 * tid + 2];
        const float b3 = fc1_b[4 * tid + 3];
        #pragma unroll
        for (int r = 0; r < ROWS; ++r) {
            float4 g;
            g.x = gelu_exact(acc[r][0] + b0);
            g.y = gelu_exact(acc[r][1] + b1);
            g.z = gelu_exact(acc[r][2] + b2);
            g.w = gelu_exact(acc[r][3] + b3);
            *(float4*)(&g_tile[r][4 * tid]) = g;
        }
    }
    __syncthreads();

    {
        float acc2[ROWS];
        #pragma unroll
        for (int r = 0; r < ROWS; ++r) acc2[r] = 0.f;

        const float* w2r = fc2_w + (size_t)tid * H1;
        for (int k = 0; k < H1; k += 4) {
            const float4 wv = *(const float4*)(w2r + k);
            #pragma unroll
            for (int r = 0; r < ROWS; ++r) {
                const float4 g = *(const float4*)(&g_tile[r][k]);
                acc2[r] += g.x * wv.x + g.y * wv.y + g.z * wv.z + g.w * wv.w;
            }
        }
        const float bias  = fc2_b[tid];
        const float gate  = modb[2 * Cn + tid];
        #pragma unroll
        for (int r = 0; r < ROWS; ++r) {
            const float v = acc2[r] + bias;
            out[(base + r) * Cn + tid] = s_tile[r][tid] + gate * v;
        }
    }
}

extern "C" void kernel_launch(void* const* d_in, const int* in_sizes, int n_in,
                              void* d_out, int out_size, void* d_ws, size_t ws_size,
                              hipStream_t stream) {
    const float* x_BLD   = (const float*)d_in[0];
    const float* c_BD    = (const float*)d_in[1];
    const float* embed_w = (const float*)d_in[2];
    const float* pos_w   = (const float*)d_in[3];
    const float* bins    = (const float*)d_in[4];
    const float* ada_w   = (const float*)d_in[5];
    const float* ada_b   = (const float*)d_in[6];
    const float* ln_g    = (const float*)d_in[7];
    const float* ln_b    = (const float*)d_in[8];
    const float* fc1_w   = (const float*)d_in[9];
    const float* fc1_b   = (const float*)d_in[10];
    const float* fc2_w   = (const float*)d_in[11];
    const float* fc2_b   = (const float*)d_in[12];
    float* out = (float*)d_out;

    float* mod   = (float*)d_ws;                       // 1536 floats (pad 2048)
    float* table = (float*)d_ws + 2048;                // 16384*256 floats = 16MB

    const size_t need = (size_t)2048 * 4 + (size_t)NCOMBO * Cn * 4;

    mod_kernel<<<(Bn * 3 * Cn) / 256, 256, 0, stream>>>(c_BD, ada_w, ada_b, mod);

    if (ws_size >= need) {
        table_kernel<<<NCOMBO / ROWS, 256, 0, stream>>>(
            embed_w, pos_w, ln_g, ln_b, fc1_w, fc1_b, fc2_w, fc2_b, mod, table);
        gather_kernel<<<Bn * Ln * 4, 256, 0, stream>>>(x_BLD, bins, table, out);
    } else {
        const int n_rows = Bn * Ln * Ln;
        main_kernel_fb<<<n_rows / ROWS, 256, 0, stream>>>(
            x_BLD, embed_w, pos_w, bins, ln_g, ln_b,
            fc1_w, fc1_b, fc2_w, fc2_b, mod, out);
    }
}

// Round 3
// 280.707 us; speedup vs baseline: 22.3552x; 3.4441x over previous
//
#include <hip/hip_runtime.h>
#include <math.h>

#define Cn 256
#define Ln 256
#define Bn 2
#define ROWS 8
#define H1 1024
#define NIDX 64
#define NREL 128
#define NCOMBO (Bn * NIDX * NREL)   // 16384
#define TROWS 32

typedef __attribute__((ext_vector_type(8))) short bf16x8;
typedef __attribute__((ext_vector_type(4))) float f32x4;

__device__ __forceinline__ float gelu_exact(float x) {
    return 0.5f * x * (1.0f + erff(x * 0.70710678118654752f));
}

__device__ __forceinline__ short f2bf(float f) {
    unsigned u = __float_as_uint(f);
    unsigned r = (u + 0x7fffu + ((u >> 16) & 1u)) >> 16;   // RNE
    return (short)r;
}

// mod = silu(c_BD) @ ada_w.T + ada_b   -> (B, 3C)
__global__ __launch_bounds__(256) void mod_kernel(
    const float* __restrict__ c_BD, const float* __restrict__ ada_w,
    const float* __restrict__ ada_b, float* __restrict__ mod)
{
    int o = blockIdx.x * 256 + threadIdx.x;
    int b = o / (3 * Cn);
    int j = o - b * (3 * Cn);
    const float* crow = c_BD + b * Cn;
    const float* wrow = ada_w + (size_t)j * Cn;
    float acc = 0.f;
    for (int k = 0; k < Cn; k += 4) {
        float4 cv = *(const float4*)(crow + k);
        float4 wv = *(const float4*)(wrow + k);
        acc += (cv.x / (1.f + expf(-cv.x))) * wv.x;
        acc += (cv.y / (1.f + expf(-cv.y))) * wv.y;
        acc += (cv.z / (1.f + expf(-cv.z))) * wv.z;
        acc += (cv.w / (1.f + expf(-cv.w))) * wv.w;
    }
    mod[o] = acc + ada_b[j];
}

// fp32 -> bf16 weight conversion (4 elems/thread)
__global__ __launch_bounds__(256) void cvt_kernel(
    const float* __restrict__ s, short* __restrict__ d, int n)
{
    int i = (blockIdx.x * 256 + threadIdx.x) * 4;
    if (i < n) {
        float4 v = *(const float4*)(s + i);
        short4 o;
        o.x = f2bf(v.x); o.y = f2bf(v.y); o.z = f2bf(v.z); o.w = f2bf(v.w);
        *(short4*)(d + i) = o;
    }
}

// MFMA table kernel: 32 combo-rows per block, fused LN -> fc1+GELU -> fc2.
__global__ __launch_bounds__(256) void table_mfma_kernel(
    const float* __restrict__ embed_w, const float* __restrict__ pos_w,
    const float* __restrict__ ln_g, const float* __restrict__ ln_b,
    const short* __restrict__ fc1bf, const float* __restrict__ fc1_b,
    const short* __restrict__ fc2bf, const float* __restrict__ fc2_b,
    const float* __restrict__ mod, float* __restrict__ table)
{
    __shared__ __align__(16) short h_lds[TROWS][264];   // LN out, bf16, padded
    __shared__ __align__(16) short g_lds[TROWS][264];   // gelu(fc1), bf16
    __shared__ float s_lds[TROWS][260];                 // pre-LN s, fp32

    const int tid  = threadIdx.x;
    const int wave = tid >> 6;
    const int lane = tid & 63;
    const int quad = lane >> 4;
    const int l15  = lane & 15;

    const int base = blockIdx.x * TROWS;
    const int b    = base >> 13;
    const int idx  = (base >> 7) & 63;
    const int rel0 = base & 127;

    const float* modb = mod + b * (3 * Cn);
    const float* erow = embed_w + (size_t)idx * Cn;

    // hoisted per-lane params (c = lane + 64m)
    float scale[4], shift[4], lng[4], lnb[4], ev[4];
    #pragma unroll
    for (int m = 0; m < 4; ++m) {
        int c = lane + 64 * m;
        scale[m] = 1.f + modb[Cn + c];
        shift[m] = modb[c];
        lng[m]   = ln_g[c];
        lnb[m]   = ln_b[c];
        ev[m]    = erow[c];
    }

    // ---- phase 1: build s + LN -> h (one row per wave-iteration) ----
    for (int r8 = 0; r8 < 8; ++r8) {
        const int rr = wave * 8 + r8;
        const float* prow = pos_w + (size_t)(rel0 + rr) * Cn;
        float sv[4]; float sum = 0.f;
        #pragma unroll
        for (int m = 0; m < 4; ++m) {
            float v = (ev[m] + prow[lane + 64 * m]) * scale[m] + shift[m];
            sv[m] = v; sum += v;
        }
        #pragma unroll
        for (int off = 32; off; off >>= 1) sum += __shfl_xor(sum, off, 64);
        float mu = sum * (1.f / Cn);
        float p2 = 0.f;
        #pragma unroll
        for (int m = 0; m < 4; ++m) { float t = sv[m] - mu; p2 += t * t; }
        #pragma unroll
        for (int off = 32; off; off >>= 1) p2 += __shfl_xor(p2, off, 64);
        float rstd = rsqrtf(p2 * (1.f / Cn) + 1e-5f);
        #pragma unroll
        for (int m = 0; m < 4; ++m) {
            int c = lane + 64 * m;
            s_lds[rr][c] = sv[m];
            h_lds[rr][c] = f2bf((sv[m] - mu) * rstd * lng[m] + lnb[m]);
        }
    }
    __syncthreads();

    f32x4 acc2[2][4];
    #pragma unroll
    for (int mt = 0; mt < 2; ++mt)
        #pragma unroll
        for (int nt = 0; nt < 4; ++nt) acc2[mt][nt] = (f32x4){0.f, 0.f, 0.f, 0.f};

    for (int c = 0; c < 4; ++c) {          // chunk of 256 H1 columns
        // GEMM1: z[32 x 256] = h @ W1c^T
        f32x4 z[2][4];
        #pragma unroll
        for (int mt = 0; mt < 2; ++mt)
            #pragma unroll
            for (int nt = 0; nt < 4; ++nt) z[mt][nt] = (f32x4){0.f, 0.f, 0.f, 0.f};

        #pragma unroll
        for (int ks = 0; ks < 8; ++ks) {
            int k0 = ks * 32 + quad * 8;
            bf16x8 a0 = *(const bf16x8*)(&h_lds[l15][k0]);
            bf16x8 a1 = *(const bf16x8*)(&h_lds[16 + l15][k0]);
            #pragma unroll
            for (int nt = 0; nt < 4; ++nt) {
                int n = c * 256 + wave * 64 + nt * 16 + l15;
                bf16x8 bf = *(const bf16x8*)(fc1bf + (size_t)n * Cn + k0);
                z[0][nt] = __builtin_amdgcn_mfma_f32_16x16x32_bf16(a0, bf, z[0][nt], 0, 0, 0);
                z[1][nt] = __builtin_amdgcn_mfma_f32_16x16x32_bf16(a1, bf, z[1][nt], 0, 0, 0);
            }
        }
        __syncthreads();   // previous chunk's GEMM2 done reading g_lds
        #pragma unroll
        for (int mt = 0; mt < 2; ++mt)
            #pragma unroll
            for (int nt = 0; nt < 4; ++nt) {
                int coll = wave * 64 + nt * 16 + l15;
                float bias = fc1_b[c * 256 + coll];
                #pragma unroll
                for (int r = 0; r < 4; ++r) {
                    int row = mt * 16 + quad * 4 + r;
                    g_lds[row][coll] = f2bf(gelu_exact(z[mt][nt][r] + bias));
                }
            }
        __syncthreads();
        // GEMM2 partial: acc2 += g @ W2c^T
        #pragma unroll
        for (int ks = 0; ks < 8; ++ks) {
            int k0 = ks * 32 + quad * 8;
            bf16x8 a0 = *(const bf16x8*)(&g_lds[l15][k0]);
            bf16x8 a1 = *(const bf16x8*)(&g_lds[16 + l15][k0]);
            #pragma unroll
            for (int nt = 0; nt < 4; ++nt) {
                int n = wave * 64 + nt * 16 + l15;
                bf16x8 bf = *(const bf16x8*)(fc2bf + (size_t)n * H1 + c * 256 + k0);
                acc2[0][nt] = __builtin_amdgcn_mfma_f32_16x16x32_bf16(a0, bf, acc2[0][nt], 0, 0, 0);
                acc2[1][nt] = __builtin_amdgcn_mfma_f32_16x16x32_bf16(a1, bf, acc2[1][nt], 0, 0, 0);
            }
        }
    }

    // epilogue: + fc2_b, gated residual, write table rows
    #pragma unroll
    for (int nt = 0; nt < 4; ++nt) {
        int col = wave * 64 + nt * 16 + l15;
        float bias = fc2_b[col];
        float gate = modb[2 * Cn + col];
        #pragma unroll
        for (int mt = 0; mt < 2; ++mt)
            #pragma unroll
            for (int r = 0; r < 4; ++r) {
                int row = mt * 16 + quad * 4 + r;
                float v = acc2[mt][nt][r] + bias;
                table[(size_t)(base + row) * Cn + col] = s_lds[row][col] + gate * v;
            }
    }
}

// gather: idx precomputed once per j (not per lane), then pure row copy.
__global__ __launch_bounds__(256) void gather_kernel(
    const float* __restrict__ x, const float* __restrict__ bins,
    const float* __restrict__ table, float* __restrict__ out)
{
    __shared__ float xs[Ln * 3];
    __shared__ float bins_s[63];
    __shared__ int   idx_s[64];

    const int tid = threadIdx.x;
    const int blk = blockIdx.x;          // (b*256 + i)*4 + q
    const int q   = blk & 3;
    const int bi  = blk >> 2;
    const int b   = bi >> 8;
    const int i   = bi & 255;

    for (int t = tid; t < Ln * 3; t += 256) xs[t] = x[(size_t)b * Ln * 3 + t];
    if (tid < 63) bins_s[tid] = bins[tid];
    __syncthreads();

    if (tid < 64) {
        int j = q * 64 + tid;
        float d0 = xs[3 * i]     - xs[3 * j];
        float d1 = xs[3 * i + 1] - xs[3 * j + 1];
        float d2 = xs[3 * i + 2] - xs[3 * j + 2];
        float d = d0 * d0 + d1 * d1 + d2 * d2;
        int v = 0;
        #pragma unroll
        for (int k = 0; k < 63; ++k) v += (bins_s[k] < d) ? 1 : 0;
        idx_s[tid] = v;
    }
    __syncthreads();

    const int wave = tid >> 6;
    const int lane = tid & 63;
    float4* outp = (float4*)(out + (size_t)bi * Ln * Cn);
    const float4* tab4 = (const float4*)table;

    #pragma unroll 4
    for (int jj = 0; jj < 16; ++jj) {
        int jl = wave * 16 + jj;
        int j  = q * 64 + jl;
        int idx = idx_s[jl];
        int rel = i - j;
        rel = (rel < -64 ? -64 : (rel > 63 ? 63 : rel)) + 64;
        size_t trow = (size_t)((b * NIDX + idx) * NREL + rel) * (Cn / 4);
        outp[(size_t)j * (Cn / 4) + lane] = tab4[trow + lane];
    }
}

// ---------------- tier-2: fp32 table kernel (round-2 proven) ----------------
__global__ __launch_bounds__(256) void table_kernel(
    const float* __restrict__ embed_w, const float* __restrict__ pos_w,
    const float* __restrict__ ln_g, const float* __restrict__ ln_b,
    const float* __restrict__ fc1_w, const float* __restrict__ fc1_b,
    const float* __restrict__ fc2_w, const float* __restrict__ fc2_b,
    const float* __restrict__ mod, float* __restrict__ table)
{
    __shared__ float s_tile[ROWS][Cn];
    __shared__ float h_tile[ROWS][Cn];
    __shared__ float g_tile[ROWS][H1];

    const int tid  = threadIdx.x;
    const int wave = tid >> 6;
    const int lane = tid & 63;

    const int base = blockIdx.x * ROWS;
    const int b    = base >> 13;
    const int idx  = (base >> 7) & 63;
    const int rel0 = base & 127;

    const float* modb = mod + b * (3 * Cn);
    const float* erow = embed_w + (size_t)idx * Cn;

    for (int rr = wave; rr < ROWS; rr += 4) {
        const float* prow = pos_w + (size_t)(rel0 + rr) * Cn;
        float sv[4]; float partial = 0.f;
        #pragma unroll
        for (int m = 0; m < 4; ++m) {
            const int c = lane + 64 * m;
            const float v = (erow[c] + prow[c]) * (1.f + modb[Cn + c]) + modb[c];
            sv[m] = v; partial += v;
        }
        float sum = partial;
        #pragma unroll
        for (int off = 32; off; off >>= 1) sum += __shfl_xor(sum, off, 64);
        const float mu = sum * (1.f / Cn);
        float p2 = 0.f;
        #pragma unroll
        for (int m = 0; m < 4; ++m) { const float t = sv[m] - mu; p2 += t * t; }
        float vs = p2;
        #pragma unroll
        for (int off = 32; off; off >>= 1) vs += __shfl_xor(vs, off, 64);
        const float rstd = rsqrtf(vs * (1.f / Cn) + 1e-5f);
        #pragma unroll
        for (int m = 0; m < 4; ++m) {
            const int c = lane + 64 * m;
            s_tile[rr][c] = sv[m];
            h_tile[rr][c] = (sv[m] - mu) * rstd * ln_g[c] + ln_b[c];
        }
    }
    __syncthreads();

    {
        float acc[ROWS][4];
        #pragma unroll
        for (int r = 0; r < ROWS; ++r)
            #pragma unroll
            for (int m = 0; m < 4; ++m) acc[r][m] = 0.f;

        const float* w0 = fc1_w + (size_t)(4 * tid + 0) * Cn;
        const float* w1 = fc1_w + (size_t)(4 * tid + 1) * Cn;
        const float* w2 = fc1_w + (size_t)(4 * tid + 2) * Cn;
        const float* w3 = fc1_w + (size_t)(4 * tid + 3) * Cn;

        for (int k = 0; k < Cn; k += 4) {
            const float4 a0 = *(const float4*)(w0 + k);
            const float4 a1 = *(const float4*)(w1 + k);
            const float4 a2 = *(const float4*)(w2 + k);
            const float4 a3 = *(const float4*)(w3 + k);
            #pragma unroll
            for (int r = 0; r < ROWS; ++r) {
                const float4 h4 = *(const float4*)(&h_tile[r][k]);
                acc[r][0] += h4.x * a0.x + h4.y * a0.y + h4.z * a0.z + h4.w * a0.w;
                acc[r][1] += h4.x * a1.x + h4.y * a1.y + h4.z * a1.z + h4.w * a1.w;
                acc[r][2] += h4.x * a2.x + h4.y * a2.y + h4.z * a2.z + h4.w * a2.w;
                acc[r][3] += h4.x * a3.x + h4.y * a3.y + h4.z * a3.z + h4.w * a3.w;
            }
        }
        const float b0 = fc1_b[4 * tid + 0];
        const float b1 = fc1_b[4 * tid + 1];
        const float b2 = fc1_b[4 * tid + 2];
        const float b3 = fc1_b[4 * tid + 3];
        #pragma unroll
        for (int r = 0; r < ROWS; ++r) {
            float4 g;
            g.x = gelu_exact(acc[r][0] + b0);
            g.y = gelu_exact(acc[r][1] + b1);
            g.z = gelu_exact(acc[r][2] + b2);
            g.w = gelu_exact(acc[r][3] + b3);
            *(float4*)(&g_tile[r][4 * tid]) = g;
        }
    }
    __syncthreads();

    {
        float acc2[ROWS];
        #pragma unroll
        for (int r = 0; r < ROWS; ++r) acc2[r] = 0.f;

        const float* w2r = fc2_w + (size_t)tid * H1;
        for (int k = 0; k < H1; k += 4) {
            const float4 wv = *(const float4*)(w2r + k);
            #pragma unroll
            for (int r = 0; r < ROWS; ++r) {
                const float4 g = *(const float4*)(&g_tile[r][k]);
                acc2[r] += g.x * wv.x + g.y * wv.y + g.z * wv.z + g.w * wv.w;
            }
        }
        const float bias = fc2_b[tid];
        const float gate = modb[2 * Cn + tid];
        #pragma unroll
        for (int r = 0; r < ROWS; ++r)
            table[(size_t)(base + r) * Cn + tid] = s_tile[r][tid] + gate * (acc2[r] + bias);
    }
}

// ---------------- tier-1: direct fallback (round-1) ----------------
__global__ __launch_bounds__(256) void main_kernel_fb(
    const float* __restrict__ x, const float* __restrict__ embed_w,
    const float* __restrict__ pos_w, const float* __restrict__ bins,
    const float* __restrict__ ln_g, const float* __restrict__ ln_b,
    const float* __restrict__ fc1_w, const float* __restrict__ fc1_b,
    const float* __restrict__ fc2_w, const float* __restrict__ fc2_b,
    const float* __restrict__ mod, float* __restrict__ out)
{
    __shared__ float s_tile[ROWS][Cn];
    __shared__ float h_tile[ROWS][Cn];
    __shared__ float g_tile[ROWS][H1];
    __shared__ float bins_s[64];

    const int tid  = threadIdx.x;
    const int wave = tid >> 6;
    const int lane = tid & 63;

    const long base = (long)blockIdx.x * ROWS;
    const int  b    = (int)(base / (Ln * Ln));
    const int  rem  = (int)(base % (Ln * Ln));
    const int  i    = rem / Ln;
    const int  j0   = rem % Ln;

    if (tid < 63) bins_s[tid] = bins[tid];
    __syncthreads();

    const float* xi = x + ((long)b * Ln + i) * 3;
    const float xi0 = xi[0], xi1 = xi[1], xi2 = xi[2];
    const float* modb = mod + b * (3 * Cn);

    for (int rr = wave; rr < ROWS; rr += 4) {
        const int j = j0 + rr;
        const float* xj = x + ((long)b * Ln + j) * 3;
        const float d0 = xi0 - xj[0], d1 = xi1 - xj[1], d2 = xi2 - xj[2];
        const float d = d0 * d0 + d1 * d1 + d2 * d2;
        int idx = 0;
        #pragma unroll
        for (int k = 0; k < 63; ++k) idx += (bins_s[k] < d) ? 1 : 0;
        int rel = i - j;
        rel = (rel < -64 ? -64 : (rel > 63 ? 63 : rel)) + 64;
        const float* erow = embed_w + (size_t)idx * Cn;
        const float* prow = pos_w + (size_t)rel * Cn;

        float sv[4]; float partial = 0.f;
        #pragma unroll
        for (int m = 0; m < 4; ++m) {
            const int c = lane + 64 * m;
            const float v = (erow[c] + prow[c]) * (1.f + modb[Cn + c]) + modb[c];
            sv[m] = v; partial += v;
        }
        float sum = partial;
        #pragma unroll
        for (int off = 32; off; off >>= 1) sum += __shfl_xor(sum, off, 64);
        const float mu = sum * (1.f / Cn);
        float p2 = 0.f;
        #pragma unroll
        for (int m = 0; m < 4; ++m) { const float t = sv[m] - mu; p2 += t * t; }
        float vs = p2;
        #pragma unroll
        for (int off = 32; off; off >>= 1) vs += __shfl_xor(vs, off, 64);
        const float rstd = rsqrtf(vs * (1.f / Cn) + 1e-5f);
        #pragma unroll
        for (int m = 0; m < 4; ++m) {
            const int c = lane + 64 * m;
            s_tile[rr][c] = sv[m];
            h_tile[rr][c] = (sv[m] - mu) * rstd * ln_g[c] + ln_b[c];
        }
    }
    __syncthreads();

    {
        float acc[ROWS][4];
        #pragma unroll
        for (int r = 0; r < ROWS; ++r)
            #pragma unroll
            for (int m = 0; m < 4; ++m) acc[r][m] = 0.f;

        const float* w0 = fc1_w + (size_t)(4 * tid + 0) * Cn;
        const float* w1 = fc1_w + (size_t)(4 * tid + 1) * Cn;
        const float* w2 = fc1_w + (size_t)(4 * tid + 2) * Cn;
        const float* w3 = fc1_w + (size_t)(4 * tid + 3) * Cn;

        for (int k = 0; k < Cn; k += 4) {
            const float4 a0 = *(const float4*)(w0 + k);
            const float4 a1 = *(const float4*)(w1 + k);
            const float4 a2 = *(const float4*)(w2 + k);
            const float4 a3 = *(const float4*)(w3 + k);
            #pragma unroll
            for (int r = 0; r < ROWS; ++r) {
                const float4 h4 = *(const float4*)(&h_tile[r][k]);
                acc[r][0] += h4.x * a0.x + h4.y * a0.y + h4.z * a0.z + h4.w * a0.w;
                acc[r][1] += h4.x * a1.x + h4.y * a1.y + h4.z * a1.z + h4.w * a1.w;
                acc[r][2] += h4.x * a2.x + h4.y * a2.y + h4.z * a2.z + h4.w * a2.w;
                acc[r][3] += h4.x * a3.x + h4.y * a3.y + h4.z * a3.z + h4.w * a3.w;
            }
        }
        const float b0 = fc1_b[4 * tid + 0];
        const float b1 = fc1_b[4 * tid + 1];
        const float b2 = fc1_b[4 * tid + 2];
        const float b3 = fc1_b[4 * tid + 3];
        #pragma unroll
        for (int r = 0; r < ROWS; ++r) {
            float4 g;
            g.x = gelu_exact(acc[r][0] + b0);
            g.y = gelu_exact(acc[r][1] + b1);
            g.z = gelu_exact(acc[r][2] + b2);
            g.w = gelu_exact(acc[r][3] + b3);
            *(float4*)(&g_tile[r][4 * tid]) = g;
        }
    }
    __syncthreads();

    {
        float acc2[ROWS];
        #pragma unroll
        for (int r = 0; r < ROWS; ++r) acc2[r] = 0.f;

        const float* w2r = fc2_w + (size_t)tid * H1;
        for (int k = 0; k < H1; k += 4) {
            const float4 wv = *(const float4*)(w2r + k);
            #pragma unroll
            for (int r = 0; r < ROWS; ++r) {
                const float4 g = *(const float4*)(&g_tile[r][k]);
                acc2[r] += g.x * wv.x + g.y * wv.y + g.z * wv.z + g.w * wv.w;
            }
        }
        const float bias = fc2_b[tid];
        const float gate = modb[2 * Cn + tid];
        #pragma unroll
        for (int r = 0; r < ROWS; ++r)
            out[(base + r) * Cn + tid] = s_tile[r][tid] + gate * (acc2[r] + bias);
    }
}

extern "C" void kernel_launch(void* const* d_in, const int* in_sizes, int n_in,
                              void* d_out, int out_size, void* d_ws, size_t ws_size,
                              hipStream_t stream) {
    const float* x_BLD   = (const float*)d_in[0];
    const float* c_BD    = (const float*)d_in[1];
    const float* embed_w = (const float*)d_in[2];
    const float* pos_w   = (const float*)d_in[3];
    const float* bins    = (const float*)d_in[4];
    const float* ada_w   = (const float*)d_in[5];
    const float* ada_b   = (const float*)d_in[6];
    const float* ln_g    = (const float*)d_in[7];
    const float* ln_b    = (const float*)d_in[8];
    const float* fc1_w   = (const float*)d_in[9];
    const float* fc1_b   = (const float*)d_in[10];
    const float* fc2_w   = (const float*)d_in[11];
    const float* fc2_b   = (const float*)d_in[12];
    float* out = (float*)d_out;

    // ws layout: mod (8 KB) | fc1bf (512 KB) | fc2bf (512 KB) | table (16 MB)
    float* mod   = (float*)d_ws;
    short* fc1bf = (short*)((char*)d_ws + 8192);
    short* fc2bf = fc1bf + Cn * H1;
    float* table = (float*)((char*)d_ws + 8192 + 2 * Cn * H1 * sizeof(short));

    const size_t need3 = 8192 + 2 * (size_t)Cn * H1 * sizeof(short)
                       + (size_t)NCOMBO * Cn * sizeof(float);
    const size_t need2 = 8192 + (size_t)NCOMBO * Cn * sizeof(float);

    mod_kernel<<<(Bn * 3 * Cn) / 256, 256, 0, stream>>>(c_BD, ada_w, ada_b, mod);

    if (ws_size >= need3) {
        cvt_kernel<<<(Cn * H1 / 4 + 255) / 256, 256, 0, stream>>>(fc1_w, fc1bf, Cn * H1);
        cvt_kernel<<<(Cn * H1 / 4 + 255) / 256, 256, 0, stream>>>(fc2_w, fc2bf, Cn * H1);
        table_mfma_kernel<<<NCOMBO / TROWS, 256, 0, stream>>>(
            embed_w, pos_w, ln_g, ln_b, fc1bf, fc1_b, fc2bf, fc2_b, mod, table);
        gather_kernel<<<Bn * Ln * 4, 256, 0, stream>>>(x_BLD, bins, table, out);
    } else if (ws_size >= need2) {
        float* table2 = (float*)((char*)d_ws + 8192);
        table_kernel<<<NCOMBO / ROWS, 256, 0, stream>>>(
            embed_w, pos_w, ln_g, ln_b, fc1_w, fc1_b, fc2_w, fc2_b, mod, table2);
        gather_kernel<<<Bn * Ln * 4, 256, 0, stream>>>(x_BLD, bins, table2, out);
    } else {
        main_kernel_fb<<<(Bn * Ln * Ln) / ROWS, 256, 0, stream>>>(
            x_BLD, embed_w, pos_w, bins, ln_g, ln_b,
            fc1_w, fc1_b, fc2_w, fc2_b, mod, out);
    }
}

// Round 4
// 255.711 us; speedup vs baseline: 24.5404x; 1.0978x over previous
//
#include <hip/hip_runtime.h>
#include <math.h>

#define Cn 256
#define Ln 256
#define Bn 2
#define H1 1024
#define NIDX 64
#define NREL 128
#define NCOMBO 16384
#define BK 64
#define TROWS 32

typedef __attribute__((ext_vector_type(8))) short bf16x8;
typedef __attribute__((ext_vector_type(4))) float f32x4;
typedef unsigned int u32;

__device__ __forceinline__ float gelu_exact(float x) {
    return 0.5f * x * (1.0f + erff(x * 0.70710678118654752f));
}
__device__ __forceinline__ short f2bf(float f) {
    unsigned u = __float_as_uint(f);
    return (short)((u + 0x7fffu + ((u >> 16) & 1u)) >> 16);   // RNE
}
// async global->LDS, 16B/lane. lds base must be wave-uniform; HW adds lane*16.
__device__ __forceinline__ void async16(const void* g, void* l) {
    __builtin_amdgcn_global_load_lds((const __attribute__((address_space(1))) u32*)g,
                                     (__attribute__((address_space(3))) u32*)l, 16, 0, 0);
}

// ---------------- mod = silu(c) @ ada_w^T + ada_b -> (B, 3C) ----------------
__global__ __launch_bounds__(256) void mod_kernel(
    const float* __restrict__ c_BD, const float* __restrict__ ada_w,
    const float* __restrict__ ada_b, float* __restrict__ mod)
{
    int o = blockIdx.x * 256 + threadIdx.x;
    int b = o / (3 * Cn);
    int j = o - b * (3 * Cn);
    const float* crow = c_BD + b * Cn;
    const float* wrow = ada_w + (size_t)j * Cn;
    float acc = 0.f;
    for (int k = 0; k < Cn; k += 4) {
        float4 cv = *(const float4*)(crow + k);
        float4 wv = *(const float4*)(wrow + k);
        acc += (cv.x / (1.f + expf(-cv.x))) * wv.x;
        acc += (cv.y / (1.f + expf(-cv.y))) * wv.y;
        acc += (cv.z / (1.f + expf(-cv.z))) * wv.z;
        acc += (cv.w / (1.f + expf(-cv.w))) * wv.w;
    }
    mod[o] = acc + ada_b[j];
}

// ---------------- fp32 -> bf16 weight conversion ----------------
__global__ __launch_bounds__(256) void cvt_kernel(
    const float* __restrict__ s, short* __restrict__ d, int n)
{
    int i = (blockIdx.x * 256 + threadIdx.x) * 4;
    if (i < n) {
        float4 v = *(const float4*)(s + i);
        short4 o;
        o.x = f2bf(v.x); o.y = f2bf(v.y); o.z = f2bf(v.z); o.w = f2bf(v.w);
        *(short4*)(d + i) = o;
    }
}

// ---------------- LN: s fp32 [16384][256], h bf16 [16384][256] ----------------
// lane handles 4 CONSECUTIVE channels -> float4/short4 coalesced stores.
__global__ __launch_bounds__(256) void ln_kernel(
    const float* __restrict__ embed_w, const float* __restrict__ pos_w,
    const float* __restrict__ ln_g, const float* __restrict__ ln_b,
    const float* __restrict__ mod,
    float* __restrict__ s_out, short* __restrict__ h_out)
{
    const int tid  = threadIdx.x;
    const int wave = tid >> 6;
    const int lane = tid & 63;
    const int base = blockIdx.x * 8;          // 8 combo rows / block
    const int b    = base >> 13;
    const int idx  = (base >> 7) & 63;
    const int rel0 = base & 127;
    const float* modb = mod + b * (3 * Cn);
    const int c0 = lane * 4;

    const float4 ev = *(const float4*)(embed_w + (size_t)idx * Cn + c0);
    const float4 sc = *(const float4*)(modb + Cn + c0);
    const float4 sh = *(const float4*)(modb + c0);
    const float4 lg = *(const float4*)(ln_g + c0);
    const float4 lb = *(const float4*)(ln_b + c0);

    #pragma unroll
    for (int r8 = 0; r8 < 2; ++r8) {
        const int rr  = wave * 2 + r8;        // 0..7
        const int row = base + rr;
        const float4 p = *(const float4*)(pos_w + (size_t)(rel0 + rr) * Cn + c0);
        float v0 = (ev.x + p.x) * (1.f + sc.x) + sh.x;
        float v1 = (ev.y + p.y) * (1.f + sc.y) + sh.y;
        float v2 = (ev.z + p.z) * (1.f + sc.z) + sh.z;
        float v3 = (ev.w + p.w) * (1.f + sc.w) + sh.w;
        float sum = v0 + v1 + v2 + v3;
        #pragma unroll
        for (int off = 32; off; off >>= 1) sum += __shfl_xor(sum, off, 64);
        const float mu = sum * (1.f / Cn);
        float t0 = v0 - mu, t1 = v1 - mu, t2 = v2 - mu, t3 = v3 - mu;
        float p2 = t0 * t0 + t1 * t1 + t2 * t2 + t3 * t3;
        #pragma unroll
        for (int off = 32; off; off >>= 1) p2 += __shfl_xor(p2, off, 64);
        const float rstd = rsqrtf(p2 * (1.f / Cn) + 1e-5f);

        *(float4*)(s_out + (size_t)row * Cn + c0) = (float4){v0, v1, v2, v3};
        short4 hq;
        hq.x = f2bf(t0 * rstd * lg.x + lb.x);
        hq.y = f2bf(t1 * rstd * lg.y + lb.y);
        hq.z = f2bf(t2 * rstd * lg.z + lb.z);
        hq.w = f2bf(t3 * rstd * lg.w + lb.w);
        *(short4*)(h_out + (size_t)row * Cn + c0) = hq;
    }
}

// ---------------- GEMM1: g[16384,1024] = gelu(h @ w1^T + b1), bf16 out ------
// 128x128 tile, BK=64, weights as A-operand -> lane owns 4 consecutive n.
__global__ __launch_bounds__(256) void gemm1_kernel(
    const short* __restrict__ h, const short* __restrict__ w1,
    const float* __restrict__ fc1_b, short* __restrict__ g)
{
    __shared__ __align__(16) short Alds[128 * BK];   // h tile [128 m][64 k]
    __shared__ __align__(16) short Wlds[128 * BK];   // w1 tile [128 n][64 k]

    const int tid  = threadIdx.x;
    const int wave = tid >> 6;
    const int lane = tid & 63;
    const int quad = lane >> 4;
    const int l15  = lane & 15;
    const int wm   = wave >> 1, wn = wave & 1;
    const int m0 = (blockIdx.x >> 3) * 128;
    const int n0 = (blockIdx.x & 7) * 128;

    const int srow = lane >> 3;          // staging: row within 8-row chunk
    const int skel = (lane & 7) * 8;     // staging: k element offset

    f32x4 acc[4][4];
    #pragma unroll
    for (int a = 0; a < 4; ++a)
        #pragma unroll
        for (int c = 0; c < 4; ++c) acc[a][c] = (f32x4){0.f, 0.f, 0.f, 0.f};

    for (int kt = 0; kt < Cn; kt += BK) {
        #pragma unroll
        for (int c = 0; c < 4; ++c) {
            const int r = wave * 32 + c * 8;
            async16(h  + (size_t)(m0 + r + srow) * Cn + kt + skel, Alds + r * BK);
            async16(w1 + (size_t)(n0 + r + srow) * Cn + kt + skel, Wlds + r * BK);
        }
        __syncthreads();
        #pragma unroll
        for (int ks = 0; ks < 2; ++ks) {
            bf16x8 wf[4], hf[4];
            #pragma unroll
            for (int nt = 0; nt < 4; ++nt)
                wf[nt] = *(const bf16x8*)(Wlds + (wn * 64 + nt * 16 + l15) * BK + ks * 32 + quad * 8);
            #pragma unroll
            for (int mt = 0; mt < 4; ++mt)
                hf[mt] = *(const bf16x8*)(Alds + (wm * 64 + mt * 16 + l15) * BK + ks * 32 + quad * 8);
            #pragma unroll
            for (int mt = 0; mt < 4; ++mt)
                #pragma unroll
                for (int nt = 0; nt < 4; ++nt)
                    acc[mt][nt] = __builtin_amdgcn_mfma_f32_16x16x32_bf16(
                        wf[nt], hf[mt], acc[mt][nt], 0, 0, 0);
        }
        __syncthreads();
    }

    // D layout (weights as A): row=n=quad*4+r, col=m=l15 -> short4 per tile
    #pragma unroll
    for (int mt = 0; mt < 4; ++mt) {
        const int m = m0 + wm * 64 + mt * 16 + l15;
        #pragma unroll
        for (int nt = 0; nt < 4; ++nt) {
            const int n = n0 + wn * 64 + nt * 16 + quad * 4;
            const float4 b4 = *(const float4*)(fc1_b + n);
            short4 o;
            o.x = f2bf(gelu_exact(acc[mt][nt][0] + b4.x));
            o.y = f2bf(gelu_exact(acc[mt][nt][1] + b4.y));
            o.z = f2bf(gelu_exact(acc[mt][nt][2] + b4.z));
            o.w = f2bf(gelu_exact(acc[mt][nt][3] + b4.w));
            *(short4*)(g + (size_t)m * H1 + n) = o;
        }
    }
}

// ---------------- GEMM2: table[16384,256] = s + gate*(g @ w2^T + b2) --------
// 64x128 tile, BK=64, K=1024.
__global__ __launch_bounds__(256) void gemm2_kernel(
    const short* __restrict__ g, const short* __restrict__ w2,
    const float* __restrict__ fc2_b, const float* __restrict__ s_in,
    const float* __restrict__ mod, float* __restrict__ table)
{
    __shared__ __align__(16) short Alds[64 * BK];    // g tile [64 m][64 k]
    __shared__ __align__(16) short Wlds[128 * BK];   // w2 tile [128 n][64 k]

    const int tid  = threadIdx.x;
    const int wave = tid >> 6;
    const int lane = tid & 63;
    const int quad = lane >> 4;
    const int l15  = lane & 15;
    const int wm   = wave >> 1, wn = wave & 1;
    const int m0 = (blockIdx.x >> 1) * 64;
    const int n0 = (blockIdx.x & 1) * 128;
    const int b  = m0 >> 13;
    const float* modb = mod + b * (3 * Cn);

    const int srow = lane >> 3;
    const int skel = (lane & 7) * 8;

    f32x4 acc[2][4];
    #pragma unroll
    for (int a = 0; a < 2; ++a)
        #pragma unroll
        for (int c = 0; c < 4; ++c) acc[a][c] = (f32x4){0.f, 0.f, 0.f, 0.f};

    for (int kt = 0; kt < H1; kt += BK) {
        #pragma unroll
        for (int c = 0; c < 2; ++c) {
            const int r = wave * 16 + c * 8;
            async16(g + (size_t)(m0 + r + srow) * H1 + kt + skel, Alds + r * BK);
        }
        #pragma unroll
        for (int c = 0; c < 4; ++c) {
            const int r = wave * 32 + c * 8;
            async16(w2 + (size_t)(n0 + r + srow) * H1 + kt + skel, Wlds + r * BK);
        }
        __syncthreads();
        #pragma unroll
        for (int ks = 0; ks < 2; ++ks) {
            bf16x8 wf[4], gf[2];
            #pragma unroll
            for (int nt = 0; nt < 4; ++nt)
                wf[nt] = *(const bf16x8*)(Wlds + (wn * 64 + nt * 16 + l15) * BK + ks * 32 + quad * 8);
            #pragma unroll
            for (int mt = 0; mt < 2; ++mt)
                gf[mt] = *(const bf16x8*)(Alds + (wm * 32 + mt * 16 + l15) * BK + ks * 32 + quad * 8);
            #pragma unroll
            for (int mt = 0; mt < 2; ++mt)
                #pragma unroll
                for (int nt = 0; nt < 4; ++nt)
                    acc[mt][nt] = __builtin_amdgcn_mfma_f32_16x16x32_bf16(
                        wf[nt], gf[mt], acc[mt][nt], 0, 0, 0);
        }
        __syncthreads();
    }

    #pragma unroll
    for (int mt = 0; mt < 2; ++mt) {
        const int m = m0 + wm * 32 + mt * 16 + l15;
        #pragma unroll
        for (int nt = 0; nt < 4; ++nt) {
            const int n = n0 + wn * 64 + nt * 16 + quad * 4;
            const float4 b4 = *(const float4*)(fc2_b + n);
            const float4 g4 = *(const float4*)(modb + 2 * Cn + n);
            const float4 s4 = *(const float4*)(s_in + (size_t)m * Cn + n);
            float4 o;
            o.x = s4.x + g4.x * (acc[mt][nt][0] + b4.x);
            o.y = s4.y + g4.y * (acc[mt][nt][1] + b4.y);
            o.z = s4.z + g4.z * (acc[mt][nt][2] + b4.z);
            o.w = s4.w + g4.w * (acc[mt][nt][3] + b4.w);
            *(float4*)(table + (size_t)m * Cn + n) = o;
        }
    }
}

// ---------------- gather: out[b,i,j] = table[(b,idx,rel)] ----------------
__global__ __launch_bounds__(256) void gather_kernel(
    const float* __restrict__ x, const float* __restrict__ bins,
    const float* __restrict__ table, float* __restrict__ out)
{
    __shared__ float xs[Ln * 3];
    __shared__ float bins_s[63];
    __shared__ int   idx_s[64];

    const int tid = threadIdx.x;
    const int blk = blockIdx.x;          // (b*256 + i)*4 + q
    const int q   = blk & 3;
    const int bi  = blk >> 2;
    const int b   = bi >> 8;
    const int i   = bi & 255;

    for (int t = tid; t < Ln * 3; t += 256) xs[t] = x[(size_t)b * Ln * 3 + t];
    if (tid < 63) bins_s[tid] = bins[tid];
    __syncthreads();

    if (tid < 64) {
        int j = q * 64 + tid;
        float d0 = xs[3 * i]     - xs[3 * j];
        float d1 = xs[3 * i + 1] - xs[3 * j + 1];
        float d2 = xs[3 * i + 2] - xs[3 * j + 2];
        float d = d0 * d0 + d1 * d1 + d2 * d2;
        int v = 0;
        #pragma unroll
        for (int k = 0; k < 63; ++k) v += (bins_s[k] < d) ? 1 : 0;
        idx_s[tid] = v;
    }
    __syncthreads();

    const int wave = tid >> 6;
    const int lane = tid & 63;
    float4* outp = (float4*)(out + (size_t)bi * Ln * Cn);
    const float4* tab4 = (const float4*)table;

    float4 v[16];
    #pragma unroll
    for (int jj = 0; jj < 16; ++jj) {
        int jl  = wave * 16 + jj;
        int j   = q * 64 + jl;
        int rel = i - j;
        rel = (rel < -64 ? -64 : (rel > 63 ? 63 : rel)) + 64;
        size_t trow = (size_t)((b * NIDX + idx_s[jl]) * NREL + rel) * (Cn / 4);
        v[jj] = tab4[trow + lane];
    }
    #pragma unroll
    for (int jj = 0; jj < 16; ++jj) {
        int j = q * 64 + wave * 16 + jj;
        outp[(size_t)j * (Cn / 4) + lane] = v[jj];
    }
}

// ---------------- tier-B fallback: R3 fused MFMA table kernel ----------------
__global__ __launch_bounds__(256) void table_mfma_kernel(
    const float* __restrict__ embed_w, const float* __restrict__ pos_w,
    const float* __restrict__ ln_g, const float* __restrict__ ln_b,
    const short* __restrict__ fc1bf, const float* __restrict__ fc1_b,
    const short* __restrict__ fc2bf, const float* __restrict__ fc2_b,
    const float* __restrict__ mod, float* __restrict__ table)
{
    __shared__ __align__(16) short h_lds[TROWS][264];
    __shared__ __align__(16) short g_lds[TROWS][264];
    __shared__ float s_lds[TROWS][260];

    const int tid  = threadIdx.x;
    const int wave = tid >> 6;
    const int lane = tid & 63;
    const int quad = lane >> 4;
    const int l15  = lane & 15;

    const int base = blockIdx.x * TROWS;
    const int b    = base >> 13;
    const int idx  = (base >> 7) & 63;
    const int rel0 = base & 127;

    const float* modb = mod + b * (3 * Cn);
    const float* erow = embed_w + (size_t)idx * Cn;

    float scale[4], shift[4], lng[4], lnb[4], ev[4];
    #pragma unroll
    for (int m = 0; m < 4; ++m) {
        int c = lane + 64 * m;
        scale[m] = 1.f + modb[Cn + c];
        shift[m] = modb[c];
        lng[m]   = ln_g[c];
        lnb[m]   = ln_b[c];
        ev[m]    = erow[c];
    }

    for (int r8 = 0; r8 < 8; ++r8) {
        const int rr = wave * 8 + r8;
        const float* prow = pos_w + (size_t)(rel0 + rr) * Cn;
        float sv[4]; float sum = 0.f;
        #pragma unroll
        for (int m = 0; m < 4; ++m) {
            float v = (ev[m] + prow[lane + 64 * m]) * scale[m] + shift[m];
            sv[m] = v; sum += v;
        }
        #pragma unroll
        for (int off = 32; off; off >>= 1) sum += __shfl_xor(sum, off, 64);
        float mu = sum * (1.f / Cn);
        float p2 = 0.f;
        #pragma unroll
        for (int m = 0; m < 4; ++m) { float t = sv[m] - mu; p2 += t * t; }
        #pragma unroll
        for (int off = 32; off; off >>= 1) p2 += __shfl_xor(p2, off, 64);
        float rstd = rsqrtf(p2 * (1.f / Cn) + 1e-5f);
        #pragma unroll
        for (int m = 0; m < 4; ++m) {
            int c = lane + 64 * m;
            s_lds[rr][c] = sv[m];
            h_lds[rr][c] = f2bf((sv[m] - mu) * rstd * lng[m] + lnb[m]);
        }
    }
    __syncthreads();

    f32x4 acc2[2][4];
    #pragma unroll
    for (int mt = 0; mt < 2; ++mt)
        #pragma unroll
        for (int nt = 0; nt < 4; ++nt) acc2[mt][nt] = (f32x4){0.f, 0.f, 0.f, 0.f};

    for (int c = 0; c < 4; ++c) {
        f32x4 z[2][4];
        #pragma unroll
        for (int mt = 0; mt < 2; ++mt)
            #pragma unroll
            for (int nt = 0; nt < 4; ++nt) z[mt][nt] = (f32x4){0.f, 0.f, 0.f, 0.f};

        #pragma unroll
        for (int ks = 0; ks < 8; ++ks) {
            int k0 = ks * 32 + quad * 8;
            bf16x8 a0 = *(const bf16x8*)(&h_lds[l15][k0]);
            bf16x8 a1 = *(const bf16x8*)(&h_lds[16 + l15][k0]);
            #pragma unroll
            for (int nt = 0; nt < 4; ++nt) {
                int n = c * 256 + wave * 64 + nt * 16 + l15;
                bf16x8 bf = *(const bf16x8*)(fc1bf + (size_t)n * Cn + k0);
                z[0][nt] = __builtin_amdgcn_mfma_f32_16x16x32_bf16(a0, bf, z[0][nt], 0, 0, 0);
                z[1][nt] = __builtin_amdgcn_mfma_f32_16x16x32_bf16(a1, bf, z[1][nt], 0, 0, 0);
            }
        }
        __syncthreads();
        #pragma unroll
        for (int mt = 0; mt < 2; ++mt)
            #pragma unroll
            for (int nt = 0; nt < 4; ++nt) {
                int coll = wave * 64 + nt * 16 + l15;
                float bias = fc1_b[c * 256 + coll];
                #pragma unroll
                for (int r = 0; r < 4; ++r) {
                    int row = mt * 16 + quad * 4 + r;
                    g_lds[row][coll] = f2bf(gelu_exact(z[mt][nt][r] + bias));
                }
            }
        __syncthreads();
        #pragma unroll
        for (int ks = 0; ks < 8; ++ks) {
            int k0 = ks * 32 + quad * 8;
            bf16x8 a0 = *(const bf16x8*)(&g_lds[l15][k0]);
            bf16x8 a1 = *(const bf16x8*)(&g_lds[16 + l15][k0]);
            #pragma unroll
            for (int nt = 0; nt < 4; ++nt) {
                int n = wave * 64 + nt * 16 + l15;
                bf16x8 bf = *(const bf16x8*)(fc2bf + (size_t)n * H1 + c * 256 + k0);
                acc2[0][nt] = __builtin_amdgcn_mfma_f32_16x16x32_bf16(a0, bf, acc2[0][nt], 0, 0, 0);
                acc2[1][nt] = __builtin_amdgcn_mfma_f32_16x16x32_bf16(a1, bf, acc2[1][nt], 0, 0, 0);
            }
        }
    }

    #pragma unroll
    for (int nt = 0; nt < 4; ++nt) {
        int col = wave * 64 + nt * 16 + l15;
        float bias = fc2_b[col];
        float gate = modb[2 * Cn + col];
        #pragma unroll
        for (int mt = 0; mt < 2; ++mt)
            #pragma unroll
            for (int r = 0; r < 4; ++r) {
                int row = mt * 16 + quad * 4 + r;
                float v = acc2[mt][nt][r] + bias;
                table[(size_t)(base + row) * Cn + col] = s_lds[row][col] + gate * v;
            }
    }
}

extern "C" void kernel_launch(void* const* d_in, const int* in_sizes, int n_in,
                              void* d_out, int out_size, void* d_ws, size_t ws_size,
                              hipStream_t stream) {
    const float* x_BLD   = (const float*)d_in[0];
    const float* c_BD    = (const float*)d_in[1];
    const float* embed_w = (const float*)d_in[2];
    const float* pos_w   = (const float*)d_in[3];
    const float* bins    = (const float*)d_in[4];
    const float* ada_w   = (const float*)d_in[5];
    const float* ada_b   = (const float*)d_in[6];
    const float* ln_g    = (const float*)d_in[7];
    const float* ln_b    = (const float*)d_in[8];
    const float* fc1_w   = (const float*)d_in[9];
    const float* fc1_b   = (const float*)d_in[10];
    const float* fc2_w   = (const float*)d_in[11];
    const float* fc2_b   = (const float*)d_in[12];
    float* out = (float*)d_out;

    char* ws = (char*)d_ws;
    float* mod   = (float*)ws;                               // 8 KB
    short* fc1bf = (short*)(ws + 8192);                      // 512 KB
    short* fc2bf = (short*)(ws + 8192 + 524288);             // 512 KB
    short* hbuf  = (short*)(ws + 1056768);                   // 8 MB
    float* sbuf  = (float*)(ws + 9445376);                   // 16 MB
    short* gbuf  = (short*)(ws + 26222592);                  // 32 MB
    float* tableA= (float*)(ws + 59777024);                  // 16 MB
    const size_t needA = 76554240;
    const size_t needB = 8192 + 2 * (size_t)Cn * H1 * sizeof(short)
                       + (size_t)NCOMBO * Cn * sizeof(float);

    mod_kernel<<<(Bn * 3 * Cn) / 256, 256, 0, stream>>>(c_BD, ada_w, ada_b, mod);
    cvt_kernel<<<(Cn * H1 / 4 + 255) / 256, 256, 0, stream>>>(fc1_w, fc1bf, Cn * H1);
    cvt_kernel<<<(Cn * H1 / 4 + 255) / 256, 256, 0, stream>>>(fc2_w, fc2bf, Cn * H1);

    if (ws_size >= needA) {
        ln_kernel<<<NCOMBO / 8, 256, 0, stream>>>(
            embed_w, pos_w, ln_g, ln_b, mod, sbuf, hbuf);
        gemm1_kernel<<<(NCOMBO / 128) * (H1 / 128), 256, 0, stream>>>(
            hbuf, fc1bf, fc1_b, gbuf);
        gemm2_kernel<<<(NCOMBO / 64) * (Cn / 128), 256, 0, stream>>>(
            gbuf, fc2bf, fc2_b, sbuf, mod, tableA);
        gather_kernel<<<Bn * Ln * 4, 256, 0, stream>>>(x_BLD, bins, tableA, out);
    } else {
        float* tableB = (float*)(ws + 8192 + 2 * (size_t)Cn * H1 * sizeof(short));
        (void)needB;
        table_mfma_kernel<<<NCOMBO / TROWS, 256, 0, stream>>>(
            embed_w, pos_w, ln_g, ln_b, fc1bf, fc1_b, fc2bf, fc2_b, mod, tableB);
        gather_kernel<<<Bn * Ln * 4, 256, 0, stream>>>(x_BLD, bins, tableB, out);
    }
}